// Round 5
// baseline (170.997 us; speedup 1.0000x reference)
//
#include <hip/hip_runtime.h>

typedef __attribute__((ext_vector_type(4))) float f32x4;
typedef __attribute__((ext_vector_type(2))) long long llx2;

#define MARGIN 0.1f

__device__ __forceinline__ void gload_lds16(const void* g, void* l) {
    __builtin_amdgcn_global_load_lds(
        (const __attribute__((address_space(1))) unsigned int*)g,
        (__attribute__((address_space(3))) unsigned int*)l, 16, 0, 0);
}

// Kernel 1 (fused): blocks 0..1999 convert emb f32 -> fp8 e4m3 fragment-major
// tiles (addr = tile*32768 + kk*2048 + col*512? no: kk*2048 + row*32.. see R4);
// blocks 2000..3023 prep: L2-normalize inputs -> fp8 frag-major x; neg[b].
__global__ __launch_bounds__(256) void prep_convert_kernel(
    const float* __restrict__ inputs, const float* __restrict__ emb,
    const int* __restrict__ target, unsigned short* __restrict__ x_frag,
    float* __restrict__ neg, unsigned char* __restrict__ emb8)
{
    const int t = threadIdx.x;
    __shared__ float s_ss[4], s_de[4];
    if (blockIdx.x < 2000) {
        // ---- convert: emb tile -> fp8, layout kk*2048 + col*32 + g*8 ----
        const int nt = blockIdx.x;
        const size_t src = (size_t)(nt * 64 + (t >> 2)) * 512 + (t & 3) * 8;
        unsigned char* dst = emb8 + (size_t)nt * 32768 + t * 8;
        #pragma unroll 4
        for (int i = 0; i < 16; ++i) {
            const float4 f0 = *reinterpret_cast<const float4*>(emb + src + i * 32);
            const float4 f1 = *reinterpret_cast<const float4*>(emb + src + i * 32 + 4);
            int u0 = __builtin_amdgcn_cvt_pk_fp8_f32(f0.x, f0.y, 0, false);
            u0 = __builtin_amdgcn_cvt_pk_fp8_f32(f0.z, f0.w, u0, true);
            int u1 = __builtin_amdgcn_cvt_pk_fp8_f32(f1.x, f1.y, 0, false);
            u1 = __builtin_amdgcn_cvt_pk_fp8_f32(f1.z, f1.w, u1, true);
            *reinterpret_cast<uint2*>(dst + i * 2048) =
                make_uint2((unsigned)u0, (unsigned)u1);
        }
    } else {
        // ---- prep: normalize row b, write fp8 A-frag layout + neg ----
        const int b = blockIdx.x - 2000;
        const float2 v = *reinterpret_cast<const float2*>(inputs + (size_t)b * 512 + t * 2);
        const int tgt = target[b];
        const float2 e = *reinterpret_cast<const float2*>(emb + (size_t)tgt * 512 + t * 2);
        float ss = v.x * v.x + v.y * v.y;
        float de = v.x * e.x + v.y * e.y;
        #pragma unroll
        for (int off = 32; off; off >>= 1) {
            ss += __shfl_down(ss, off);
            de += __shfl_down(de, off);
        }
        const int wid = t >> 6, lane = t & 63;
        if (lane == 0) { s_ss[wid] = ss; s_de[wid] = de; }
        __syncthreads();
        const float tss = s_ss[0] + s_ss[1] + s_ss[2] + s_ss[3];
        const float tde = s_de[0] + s_de[1] + s_de[2] + s_de[3];
        const float inv = 1.0f / fmaxf(sqrtf(tss), 1e-12f);
        const int pk = __builtin_amdgcn_cvt_pk_fp8_f32(v.x * inv, v.y * inv, 0, false);
        const int f    = b >> 4;
        const int flan = (b & 15) | (((t >> 2) & 3) << 4);
        const int kk   = t >> 4;
        const int byt  = (2 * t) & 7;
        x_frag[(f * 8192 + flan * 128 + kk * 8 + byt) >> 1] =
            (unsigned short)(pk & 0xffff);
        if (t == 0) neg[b] = tde * inv;
    }
}

// Kernel 2: A (x) resident in registers (128 VGPR), emb fp8 tiles streamed
// through double-buffered LDS via global_load_lds. PHASED schedule: each tile's
// 16 kk split into 4 phases {16 ds_read_b64 | 1 stage-load for j+1 | lgkmcnt(0)
// | setprio+64 MFMA | barrier} so waves' LDS reads overlap other waves' MFMA.
__global__ __launch_bounds__(512, 2) void gemm_frag_kernel(
    const unsigned short* __restrict__ x_frag, const unsigned char* __restrict__ emb8,
    const float* __restrict__ neg, float* __restrict__ partials)
{
    __shared__ unsigned char btile[65536];        // 2 x 32 KB double buffer
    const int t = threadIdx.x;
    const int wid = t >> 6, lane = t & 63;
    const int lrow = lane & 15, g = lane >> 4;
    const int bx = blockIdx.x;
    const int group = (bx & 7) | ((bx >> 4) << 3);     // 0..127 (mhalf pair same XCD)
    const int mhalf = (bx >> 3) & 1;
    const int cnt = (group < 80) ? 16 : 15;            // 80*16 + 48*15 = 2000

    // ---- A prologue: this wave's 64 m-rows, full K, into registers ----
    long long areg[4][16];                             // 128 VGPR
    #pragma unroll
    for (int mf = 0; mf < 4; ++mf) {
        const int f = mhalf * 32 + wid * 4 + mf;
        const llx2* base = reinterpret_cast<const llx2*>(
            x_frag + ((f * 8192 + lane * 128) >> 1));
        #pragma unroll
        for (int i = 0; i < 8; ++i)
            *reinterpret_cast<llx2*>(&areg[mf][2 * i]) = base[i];
    }

    // stage tile 0 completely
    {
        const size_t gb = (size_t)group * 32768 + wid * 4096 + lane * 16;
        #pragma unroll
        for (int p = 0; p < 4; ++p)
            gload_lds16(emb8 + gb + p * 1024, &btile[wid * 4096 + p * 1024]);
    }

    float sum = 0.0f;
    const char* lbase = reinterpret_cast<const char*>(btile) + lrow * 32 + g * 8;

    #pragma unroll 1
    for (int j = 0; j < cnt; ++j) {
        asm volatile("s_waitcnt vmcnt(0)" ::: "memory");   // tile j staged (loads are >=1 tile old)
        __builtin_amdgcn_s_barrier();
        __builtin_amdgcn_sched_barrier(0);

        f32x4 acc[4][4];
        #pragma unroll
        for (int i = 0; i < 4; ++i)
            #pragma unroll
            for (int k = 0; k < 4; ++k) acc[i][k] = (f32x4)(0.0f);

        const char* bb = lbase + (j & 1) * 32768;
        const bool more = (j + 1 < cnt);
        const size_t gbn = (size_t)(group + 128 * (j + 1)) * 32768 + wid * 4096 + lane * 16;
        unsigned char* lbn = &btile[((j + 1) & 1) * 32768 + wid * 4096];

        #pragma unroll
        for (int q = 0; q < 4; ++q) {
            long long bfr[4][4];                       // 4 kk x 4 nf
            #pragma unroll
            for (int k2 = 0; k2 < 4; ++k2)
                #pragma unroll
                for (int nf = 0; nf < 4; ++nf)
                    bfr[k2][nf] = *reinterpret_cast<const long long*>(
                        bb + (q * 4 + k2) * 2048 + nf * 512);
            if (more)                                   // 1 of 4 stage loads / phase
                gload_lds16(emb8 + gbn + q * 1024, lbn + q * 1024);
            asm volatile("s_waitcnt lgkmcnt(0)" ::: "memory");
            __builtin_amdgcn_sched_barrier(0);
            __builtin_amdgcn_s_setprio(1);
            #pragma unroll
            for (int k2 = 0; k2 < 4; ++k2)
                #pragma unroll
                for (int mf = 0; mf < 4; ++mf)
                    #pragma unroll
                    for (int nf = 0; nf < 4; ++nf)
                        acc[mf][nf] = __builtin_amdgcn_mfma_f32_16x16x32_fp8_fp8(
                            areg[mf][q * 4 + k2], bfr[k2][nf], acc[mf][nf], 0, 0, 0);
            __builtin_amdgcn_s_setprio(0);
            __builtin_amdgcn_sched_barrier(0);
            __builtin_amdgcn_s_barrier();
        }

        // ---- fused epilogue: relu(margin + dot - neg[m]) summed ----
        const int rbase = mhalf * 512 + wid * 64 + g * 4;
        #pragma unroll
        for (int mf = 0; mf < 4; ++mf) {
            const float4 nv = *reinterpret_cast<const float4*>(neg + rbase + mf * 16);
            #pragma unroll
            for (int jj = 0; jj < 4; ++jj) {
                const float thr = (&nv.x)[jj] - MARGIN;
                #pragma unroll
                for (int nf = 0; nf < 4; ++nf)
                    sum += fmaxf(acc[mf][nf][jj] - thr, 0.0f);
            }
        }
    }

    // ---- block reduction ----
    __syncthreads();
    #pragma unroll
    for (int off = 32; off; off >>= 1) sum += __shfl_down(sum, off);
    float* red = reinterpret_cast<float*>(btile);
    if (lane == 0) red[wid] = sum;
    __syncthreads();
    if (t == 0) {
        float tot = 0.f;
        #pragma unroll
        for (int w = 0; w < 8; ++w) tot += red[w];
        partials[bx] = tot;
    }
}

// Kernel 3: deterministic final reduction of 256 block partials, mean over B.
__global__ __launch_bounds__(256) void reduce_kernel(
    const float* __restrict__ partials, float* __restrict__ out)
{
    float s = 0.f;
    for (int i = threadIdx.x; i < 256; i += 256) s += partials[i];
    #pragma unroll
    for (int off = 32; off; off >>= 1) s += __shfl_down(s, off);
    __shared__ float red[4];
    const int wid = threadIdx.x >> 6, lane = threadIdx.x & 63;
    if (lane == 0) red[wid] = s;
    __syncthreads();
    if (threadIdx.x == 0)
        out[0] = (red[0] + red[1] + red[2] + red[3]) * (1.0f / 1024.0f);
}

extern "C" void kernel_launch(void* const* d_in, const int* in_sizes, int n_in,
                              void* d_out, int out_size, void* d_ws, size_t ws_size,
                              hipStream_t stream)
{
    const float* inputs = (const float*)d_in[0];
    const float* emb    = (const float*)d_in[1];
    const int*   target = (const int*)d_in[2];
    float* out = (float*)d_out;
    char*  ws  = (char*)d_ws;

    unsigned short* x_frag = (unsigned short*)ws;                   // 512 KB
    float*          neg    = (float*)(ws + 524288);                 // 4 KB
    float*          parts  = (float*)(ws + 528384);                 // 1 KB
    unsigned char*  emb8   = (unsigned char*)(ws + 1048576);        // 65.5 MB

    prep_convert_kernel<<<3024, 256, 0, stream>>>(inputs, emb, target,
                                                  x_frag, neg, emb8);
    gemm_frag_kernel<<<256, 512, 0, stream>>>(x_frag, emb8, neg, parts);
    reduce_kernel<<<1, 256, 0, stream>>>(parts, out);
}

// Round 6
// 125.831 us; speedup vs baseline: 1.3589x; 1.3589x over previous
//
#include <hip/hip_runtime.h>

typedef __attribute__((ext_vector_type(4))) float f32x4;
typedef __attribute__((ext_vector_type(4))) int   i32x4;
typedef __attribute__((ext_vector_type(8))) int   i32x8;

#define MARGIN 0.1f
#define SC1 0x7F7F7F7F   // E8M0 scale bytes = 127 -> 2^0 = 1.0

__device__ __forceinline__ void gload_lds16(const void* g, void* l) {
    __builtin_amdgcn_global_load_lds(
        (const __attribute__((address_space(1))) unsigned int*)g,
        (__attribute__((address_space(3))) unsigned int*)l, 16, 0, 0);
}

// Kernel 1 (fused): blocks 0..1999 convert emb f32 -> fp8 e4m3 in K=128
// fragment-major tiles: byte = tile*32768 + kk*8192 + h*4096 + nf*1024 + lane*16,
// holding emb[tile*64 + nf*16 + (lane&15)][kk*128 + (lane>>4)*32 + h*16 + 0..15].
// Blocks 2000..3023: L2-normalize inputs -> fp8 A-frags (f*8192 + kk*2048 +
// lane*32 + c) and neg[b] = f32 dot(x, emb[target[b]]).
__global__ __launch_bounds__(256) void prep_convert_kernel(
    const float* __restrict__ inputs, const float* __restrict__ emb,
    const int* __restrict__ target, unsigned char* __restrict__ x_frag,
    float* __restrict__ neg, unsigned char* __restrict__ emb8)
{
    const int t = threadIdx.x;
    __shared__ float s_ss[4], s_de[4];
    if (blockIdx.x < 2000) {
        const int nt = blockIdx.x;
        const int nf = t >> 6, lane = t & 63, g = lane >> 4, lrow = lane & 15;
        const float* src = emb + (size_t)(nt * 64 + nf * 16 + lrow) * 512 + g * 32;
        unsigned char* dst = emb8 + (size_t)nt * 32768 + nf * 1024 + lane * 16;
        #pragma unroll
        for (int kk = 0; kk < 4; ++kk) {
            const float4* s4 = reinterpret_cast<const float4*>(src + kk * 128);
            unsigned int w[8];
            #pragma unroll
            for (int i = 0; i < 8; ++i) {
                const float4 f = s4[i];
                int u = __builtin_amdgcn_cvt_pk_fp8_f32(f.x, f.y, 0, false);
                u = __builtin_amdgcn_cvt_pk_fp8_f32(f.z, f.w, u, true);
                w[i] = (unsigned)u;
            }
            *reinterpret_cast<uint4*>(dst + kk * 8192) =
                make_uint4(w[0], w[1], w[2], w[3]);
            *reinterpret_cast<uint4*>(dst + kk * 8192 + 4096) =
                make_uint4(w[4], w[5], w[6], w[7]);
        }
    } else {
        const int b = blockIdx.x - 2000;
        const float2 v = *reinterpret_cast<const float2*>(inputs + (size_t)b * 512 + t * 2);
        const int tgt = target[b];
        const float2 e = *reinterpret_cast<const float2*>(emb + (size_t)tgt * 512 + t * 2);
        float ss = v.x * v.x + v.y * v.y;
        float de = v.x * e.x + v.y * e.y;
        #pragma unroll
        for (int off = 32; off; off >>= 1) {
            ss += __shfl_down(ss, off);
            de += __shfl_down(de, off);
        }
        const int wid = t >> 6, lane = t & 63;
        if (lane == 0) { s_ss[wid] = ss; s_de[wid] = de; }
        __syncthreads();
        const float tss = s_ss[0] + s_ss[1] + s_ss[2] + s_ss[3];
        const float tde = s_de[0] + s_de[1] + s_de[2] + s_de[3];
        const float inv = 1.0f / fmaxf(sqrtf(tss), 1e-12f);
        const int pk = __builtin_amdgcn_cvt_pk_fp8_f32(v.x * inv, v.y * inv, 0, false);
        // A-frag: f=b>>4, lrow=b&15; k=2t: kk=t>>6, g=(t>>4)&3, c=(2t)&31
        const int addr = (b >> 4) * 8192 + (t >> 6) * 2048 +
                         (((t >> 4) & 3) * 16 + (b & 15)) * 32 + ((2 * t) & 31);
        *reinterpret_cast<unsigned short*>(x_frag + addr) =
            (unsigned short)(pk & 0xffff);
        if (t == 0) neg[b] = tde * inv;
    }
}

// Kernel 2: A (x) resident in registers (128 VGPR: 4 mf x 4 kk x i32x8),
// emb fp8 tiles streamed through double-buffered LDS via global_load_lds with
// counted vmcnt(4) (R4 skeleton). MX-scaled MFMA 16x16x128, unit scales.
// All ds_read_b128 are lane-contiguous (zero bank conflicts by construction).
__global__ __launch_bounds__(512, 2) void gemm_frag_kernel(
    const unsigned char* __restrict__ x_frag, const unsigned char* __restrict__ emb8,
    const float* __restrict__ neg, float* __restrict__ partials)
{
    __shared__ unsigned char btile[65536];        // 2 x 32 KB double buffer
    const int t = threadIdx.x;
    const int wid = t >> 6, lane = t & 63;
    const int lrow = lane & 15, g = lane >> 4;
    const int bx = blockIdx.x;
    const int group = (bx & 7) | ((bx >> 4) << 3);     // 0..127
    const int mhalf = (bx >> 3) & 1;
    const int cnt = (group < 80) ? 16 : 15;            // 80*16 + 48*15 = 2000

    // ---- A prologue: wave's 64 m-rows, full K=512 ----
    i32x8 areg[4][4];                                  // 128 VGPR
    #pragma unroll
    for (int mf = 0; mf < 4; ++mf) {
        const int f = mhalf * 32 + wid * 4 + mf;
        const i32x4* ap = reinterpret_cast<const i32x4*>(
            x_frag + (size_t)f * 8192 + lane * 32);
        #pragma unroll
        for (int kk = 0; kk < 4; ++kk) {
            const i32x4 lo = ap[kk * 128];
            const i32x4 hi = ap[kk * 128 + 1];
            areg[mf][kk] = __builtin_shufflevector(lo, hi, 0, 1, 2, 3, 4, 5, 6, 7);
        }
    }

#define STAGE(buf, tile)                                                      \
    {                                                                         \
        const size_t gb = (size_t)(tile) * 32768 + wid * 4096 + lane * 16;    \
        _Pragma("unroll")                                                     \
        for (int p = 0; p < 4; ++p)                                           \
            gload_lds16(emb8 + gb + p * 1024,                                 \
                        &btile[(buf) * 32768 + wid * 4096 + p * 1024]);       \
    }

    STAGE(0, group);                                   // tile j=0
    float sum = 0.0f;

    #pragma unroll 1
    for (int j = 0; j < cnt; ++j) {
        if (j + 1 < cnt) {
            STAGE((j + 1) & 1, group + 128 * (j + 1));
            asm volatile("s_waitcnt vmcnt(4)" ::: "memory");
        } else {
            asm volatile("s_waitcnt vmcnt(0)" ::: "memory");
        }
        __builtin_amdgcn_s_barrier();                  // tile j staged for all
        __builtin_amdgcn_sched_barrier(0);

        f32x4 acc[4][4];
        #pragma unroll
        for (int i = 0; i < 4; ++i)
            #pragma unroll
            for (int k = 0; k < 4; ++k) acc[i][k] = (f32x4)(0.0f);

        const unsigned char* bb = btile + (j & 1) * 32768 + lane * 16;
        #pragma unroll
        for (int kk = 0; kk < 4; ++kk) {
            #pragma unroll
            for (int nfp = 0; nfp < 2; ++nfp) {        // nf pairs: caps VGPRs
                i32x8 bfr[2];
                #pragma unroll
                for (int q = 0; q < 2; ++q) {
                    const int nf = nfp * 2 + q;
                    const i32x4 lo = *reinterpret_cast<const i32x4*>(
                        bb + kk * 8192 + nf * 1024);
                    const i32x4 hi = *reinterpret_cast<const i32x4*>(
                        bb + kk * 8192 + nf * 1024 + 4096);
                    bfr[q] = __builtin_shufflevector(lo, hi, 0, 1, 2, 3, 4, 5, 6, 7);
                }
                #pragma unroll
                for (int mf = 0; mf < 4; ++mf)
                    #pragma unroll
                    for (int q = 0; q < 2; ++q)
                        acc[mf][nfp * 2 + q] =
                            __builtin_amdgcn_mfma_scale_f32_16x16x128_f8f6f4(
                                areg[mf][kk], bfr[q], acc[mf][nfp * 2 + q],
                                0, 0, 0, SC1, 0, SC1);
            }
        }

        // ---- fused epilogue: relu(margin + dot - neg[m]) summed ----
        const int rbase = mhalf * 512 + wid * 64 + g * 4;
        #pragma unroll
        for (int mf = 0; mf < 4; ++mf) {
            const float4 nv = *reinterpret_cast<const float4*>(neg + rbase + mf * 16);
            #pragma unroll
            for (int jj = 0; jj < 4; ++jj) {
                const float thr = (&nv.x)[jj] - MARGIN;
                #pragma unroll
                for (int nf = 0; nf < 4; ++nf)
                    sum += fmaxf(acc[mf][nf][jj] - thr, 0.0f);
            }
        }
        __builtin_amdgcn_sched_barrier(0);
        __builtin_amdgcn_s_barrier();                  // all done reading buf[j&1]
    }

    // ---- block reduction ----
    __syncthreads();
    #pragma unroll
    for (int off = 32; off; off >>= 1) sum += __shfl_down(sum, off);
    float* red = reinterpret_cast<float*>(btile);
    if (lane == 0) red[wid] = sum;
    __syncthreads();
    if (t == 0) {
        float tot = 0.f;
        #pragma unroll
        for (int w = 0; w < 8; ++w) tot += red[w];
        partials[bx] = tot;
    }
}

// Kernel 3: deterministic final reduction of 256 block partials, mean over B.
__global__ __launch_bounds__(256) void reduce_kernel(
    const float* __restrict__ partials, float* __restrict__ out)
{
    float s = partials[threadIdx.x];
    #pragma unroll
    for (int off = 32; off; off >>= 1) s += __shfl_down(s, off);
    __shared__ float red[4];
    const int wid = threadIdx.x >> 6, lane = threadIdx.x & 63;
    if (lane == 0) red[wid] = s;
    __syncthreads();
    if (threadIdx.x == 0)
        out[0] = (red[0] + red[1] + red[2] + red[3]) * (1.0f / 1024.0f);
}

extern "C" void kernel_launch(void* const* d_in, const int* in_sizes, int n_in,
                              void* d_out, int out_size, void* d_ws, size_t ws_size,
                              hipStream_t stream)
{
    const float* inputs = (const float*)d_in[0];
    const float* emb    = (const float*)d_in[1];
    const int*   target = (const int*)d_in[2];
    float* out = (float*)d_out;
    char*  ws  = (char*)d_ws;

    unsigned char* x_frag = (unsigned char*)ws;                     // 512 KB
    float*         neg    = (float*)(ws + 524288);                  // 4 KB
    float*         parts  = (float*)(ws + 528384);                  // 1 KB
    unsigned char* emb8   = (unsigned char*)(ws + 1048576);         // 65.5 MB

    prep_convert_kernel<<<3024, 256, 0, stream>>>(inputs, emb, target,
                                                  x_frag, neg, emb8);
    gemm_frag_kernel<<<256, 512, 0, stream>>>(x_frag, emb8, neg, parts);
    reduce_kernel<<<1, 256, 0, stream>>>(parts, out);
}